// Round 11
// baseline (389.690 us; speedup 1.0000x reference)
//
#include <hip/hip_runtime.h>
#include <math.h>
#include <stdint.h>

#define V_N 100000
#define E_N 300000
#define D_N 128
#define EPSV 1e-5f
#define NCHUNK 391   // ceil(V_N/256)
#define MPAD 100096  // 1564 * 64
#define NBLK_G 782   // MPAD/128 gemm blocks (128-row tiles)
#define NSH 8        // stats shards

typedef _Float16 f16;
typedef f16 f16x8 __attribute__((ext_vector_type(8)));
typedef f16 f16x4 __attribute__((ext_vector_type(4)));
typedef f16 f16x2 __attribute__((ext_vector_type(2)));
typedef float f32x4 __attribute__((ext_vector_type(4)));

// async global->LDS, 16B per lane; lds base must be wave-uniform
#define GLD(g, l) __builtin_amdgcn_global_load_lds( \
    (__attribute__((address_space(1))) void*)(g),   \
    (__attribute__((address_space(3))) void*)(l), 16, 0, 0)

// ----------------- merged: edge-degree count + weight prep + feature cast -----------------
// blocks [0,2344): count; [2344,2728): Wcat[l][n][k] half, k=[W0 row|W1 row]; rest: f16 cast.
__global__ __launch_bounds__(256) void k_countprep(const int* __restrict__ edges, int* __restrict__ deg,
                                                   const float* __restrict__ W0, const float* __restrict__ W1,
                                                   f16* __restrict__ Wc, const float* __restrict__ x,
                                                   f16* __restrict__ y) {
  int b = blockIdx.x;
  if (b < 2344) {
    int i = b * 256 + threadIdx.x;
    if (i < 2 * E_N) atomicAdd(&deg[edges[i]], 1);
  } else if (b < 2344 + 384) {  // 384*256 == 3*128*256 exactly
    int idx = (b - 2344) * 256 + threadIdx.x;
    int l = idx >> 15;
    int rem = idx & 32767;
    int n = rem >> 8, k = rem & 255;
    float v = (k < 128) ? W0[l * 16384 + n * 128 + k] : W1[l * 16384 + n * 128 + (k - 128)];
    Wc[idx] = (f16)v;
  } else {
    int q = (b - 2344 - 384) * 256 + threadIdx.x;  // 12500*256 == V_N*32 exactly
    float4 xv = ((const float4*)x)[q];
    f16x4 h;
    h[0] = (f16)xv.x; h[1] = (f16)xv.y; h[2] = (f16)xv.z; h[3] = (f16)xv.w;
    *(f16x4*)&y[(size_t)q * 4] = h;
  }
}

__global__ __launch_bounds__(256) void k_chunksum(const int* __restrict__ deg, int* __restrict__ csum) {
  __shared__ int red[256];
  int c = blockIdx.x, t = threadIdx.x;
  int i = c * 256 + t;
  red[t] = (i < V_N) ? deg[i] : 0;
  __syncthreads();
  for (int s = 128; s > 0; s >>= 1) {
    if (t < s) red[t] += red[t + s];
    __syncthreads();
  }
  if (t == 0) csum[c] = red[0];
}

// per-block redundant chunk-offset (sum csum[j<c], L2-hot) replaces the k_scanchunks
// dispatch; then intra-chunk scan. Also zeroes the fill cursor (deg stays = true degree).
__global__ __launch_bounds__(256) void k_writeoff(const int* __restrict__ deg, const int* __restrict__ csum,
                                                  int* __restrict__ csr_off, float* __restrict__ dinv,
                                                  float* __restrict__ degf, int* __restrict__ cursor) {
  __shared__ int sh[256];
  __shared__ int sbase;
  int c = blockIdx.x, t = threadIdx.x;
  // exclusive chunk offset: sum of csum[0..c-1]
  int x = (t < c) ? csum[t] : 0;
  if (256 + t < c) x += csum[256 + t];  // c <= 390 < 512
  sh[t] = x;
  __syncthreads();
  for (int s = 128; s > 0; s >>= 1) {
    if (t < s) sh[t] += sh[t + s];
    __syncthreads();
  }
  if (t == 0) sbase = sh[0];
  __syncthreads();
  int base = sbase;
  __syncthreads();  // done reading sh[0]; safe to reuse sh
  int i = c * 256 + t;
  int v = (i < V_N) ? deg[i] : 0;
  sh[t] = v;
  __syncthreads();
  for (int s = 1; s < 256; s <<= 1) {
    int xx = (t >= s) ? sh[t - s] : 0;
    __syncthreads();
    sh[t] += xx;
    __syncthreads();
  }
  int excl = sh[t] - v;
  if (i <= V_N) csr_off[i] = base + excl;
  if (i < V_N) {
    dinv[i] = 1.0f / (1.0f + (float)v);
    degf[i] = (float)v;
    cursor[i] = 0;
  }
}

// fills CSR adj AND the ELL8 fast-path array (first 8 neighbors at adjell[v*8+j]).
// Slots j >= deg stay uninitialized (workspace garbage) -> consumer clamps before use.
__global__ __launch_bounds__(256) void k_fill(const int* __restrict__ edges, const int* __restrict__ csr_off,
                                              int* __restrict__ cursor, int* __restrict__ adj,
                                              int* __restrict__ adjell) {
  int e = blockIdx.x * blockDim.x + threadIdx.x;
  if (e >= E_N) return;
  int s = edges[2 * e], d = edges[2 * e + 1];
  int p = atomicAdd(&cursor[s], 1);
  adj[csr_off[s] + p] = d;
  if (p < 8) adjell[s * 8 + p] = d;
  int q = atomicAdd(&cursor[d], 1);
  adj[csr_off[d] + q] = s;
  if (q < 8) adjell[d * 8 + q] = s;
}

// ----------------- gather: quad-per-vertex, dwordx4 row loads, packed-f16 math ----------
// Wave = 4 quads; quad q owns one vertex, lane l16 owns one 16B channel chunk (8 halves).
// MODE 0: neighbors from y (raw). MODE 1: neighbors from tin with relu(scale*t+shift),
//   scale/shift recomputed per block from statsP (8 shards from the previous gemm).
// f16 accumulation throughout. __launch_bounds__(256,8) pins <=64 VGPR -> 32 waves/CU.
// Blocks 0..7 zero statsN. Grid: 6250 x 4 waves x 4 quads = 100000.
template <int MODE>
__global__ __launch_bounds__(256, 8) void k_gather(const f16* __restrict__ tin, const f16* __restrict__ y,
                                                   f16* __restrict__ xa, const int* __restrict__ deg,
                                                   const int* __restrict__ csr_off,
                                                   const int* __restrict__ adjell, const int* __restrict__ adj,
                                                   const float* __restrict__ gamma, const float* __restrict__ beta,
                                                   const float* __restrict__ statsP, float* __restrict__ statsN) {
  __shared__ float sred[256];
  __shared__ float scl[128], sfl[128];
  int tid = threadIdx.x;
  if (blockIdx.x < NSH) statsN[blockIdx.x * 256 + tid] = 0.f;
  int w = tid >> 6, lane = tid & 63;
  int q = lane >> 4, l16 = lane & 15;
  int v = (blockIdx.x * 4 + w) * 4 + q;  // this lane's vertex (exactly covers [0, V_N))
  int co = l16 * 8;                      // channel base, 8 halves = 16B
  const f16* base = MODE ? tin : y;
  int dg = deg[v];
  int s0 = csr_off[v];
  int4 ia = *(const int4*)&adjell[v * 8];
  int4 ib = *(const int4*)&adjell[v * 8 + 4];
  f16x8 scv = {}, sfv = {};
  if (MODE) {
    // per-block redundant BN finalize (identical f32 math in every block)
    float a = 0.f;
#pragma unroll
    for (int h = 0; h < NSH; ++h) a += statsP[h * 256 + tid];
    sred[tid] = a;
    __syncthreads();
    if (tid < 128) {
      float s = sred[tid], sq = sred[128 + tid];
      float mu = s * (1.0f / V_N);
      float var = sq * (1.0f / V_N) - mu * mu;
      float scvf = gamma[tid] * rsqrtf(var + EPSV);
      scl[tid] = scvf;
      sfl[tid] = beta[tid] - mu * scvf;
    }
    __syncthreads();
#pragma unroll
    for (int k = 0; k < 8; ++k) {
      scv[k] = (f16)scl[co + k];
      sfv[k] = (f16)sfl[co + k];
    }
  }
  int idx[8] = {ia.x, ia.y, ia.z, ia.w, ib.x, ib.y, ib.z, ib.w};
#pragma unroll
  for (int j = 0; j < 8; ++j) idx[j] = ((unsigned)idx[j] < (unsigned)V_N) ? idx[j] : 0;
  f16x8 h[8];
#pragma unroll
  for (int j = 0; j < 8; ++j) h[j] = *(const f16x8*)&base[(size_t)idx[j] * 128 + co];
  f16x8 zero = {};
#pragma unroll
  for (int j = 0; j < 8; ++j) {
    f16x8 u = h[j];
    if (MODE) u = __builtin_elementwise_max(scv * u + sfv, zero);
    h[j] = (j < dg) ? u : zero;
  }
  f16x8 t01 = h[0] + h[1], t23 = h[2] + h[3], t45 = h[4] + h[5], t67 = h[6] + h[7];
  f16x8 accv = (t01 + t23) + (t45 + t67);
  // tail for deg > 8 (divergent at quad granularity; P ~ 11% of vertices)
  for (int p = 8; p < dg; p += 8) {
    int id2[8];
#pragma unroll
    for (int j = 0; j < 8; ++j) {
      int pp = p + j;
      id2[j] = adj[s0 + (pp < dg ? pp : dg - 1)];
    }
    f16x8 g[8];
#pragma unroll
    for (int j = 0; j < 8; ++j) g[j] = *(const f16x8*)&base[(size_t)id2[j] * 128 + co];
#pragma unroll
    for (int j = 0; j < 8; ++j) {
      f16x8 u = g[j];
      if (MODE) u = __builtin_elementwise_max(scv * u + sfv, zero);
      g[j] = (p + j < dg) ? u : zero;
    }
    accv = accv + (((g[0] + g[1]) + (g[2] + g[3])) + ((g[4] + g[5]) + (g[6] + g[7])));
  }
  *(f16x8*)&xa[(size_t)v * 128 + co] = accv;
}

// ----------------- fused GEMM: t = dinv * ([act|xa] @ Wcat^T + b0 + deg*b1); + BN stats ---
// 128 rows x 128 cols per block (782 blocks), K=256 in 4 chunks of 64 halves.
// R9 barriered structure; B fragments go global->REGISTER (16 x f16x8/lane per kc,
// L2-hot Wcat) instead of global->LDS->reg: no Bs LDS (50->18KB), B off the post-barrier
// critical path. A staged via GLD (or reg-staged with BN+relu in MODE 1, in-place safe).
template <int MODE>
__global__ __launch_bounds__(256) void k_gemm(const f16* ysrc, const f16* __restrict__ xa,
                                              const f16* __restrict__ Wc,
                                              const float* __restrict__ b0, const float* __restrict__ b1,
                                              const float* __restrict__ dinv, const float* __restrict__ degf,
                                              const float* __restrict__ gammaP, const float* __restrict__ betaP,
                                              const float* __restrict__ statsP, float* __restrict__ statsN,
                                              f16* tbuf) {
  __shared__ __align__(16) f16 As[128 * 64];   // 1024 x 16B chunks, chunk (r,c) at slot r*8 + (c^(r&7))
  __shared__ float sstat[256];
  __shared__ __align__(16) f16 scf[128], shf[128];
  int tid = threadIdx.x;
  int w = tid >> 6, lane = tid & 63;
  int quad = lane >> 4, l16 = lane & 15;
  int row0 = blockIdx.x * 128;
  f32x4 acc[2][8] = {};
  if (MODE) {
    // per-block redundant BN finalize of the PREVIOUS layer (uses sstat as scratch)
    float a = 0.f;
#pragma unroll
    for (int h = 0; h < NSH; ++h) a += statsP[h * 256 + tid];
    sstat[tid] = a;
    __syncthreads();
    if (tid < 128) {
      float s = sstat[tid], sq = sstat[128 + tid];
      float mu = s * (1.0f / V_N);
      float var = sq * (1.0f / V_N) - mu * mu;
      float scv = gammaP[tid] * rsqrtf(var + EPSV);
      scf[tid] = (f16)scv;
      shf[tid] = (f16)(betaP[tid] - mu * scv);
    }
    __syncthreads();
  }
  sstat[tid] = 0.f;  // visible before epilogue use via the kc-loop barriers

#pragma unroll 1
  for (int kc = 0; kc < 4; ++kc) {
    if (MODE && kc < 2) {
      // reg-stage A from t with on-the-fly BN+relu (identical f16 math to gather's path)
      int koff = kc * 64;
      f16x8 zero = {};
#pragma unroll
      for (int i = 0; i < 4; ++i) {
        int s = (w * 4 + i) * 64 + lane;
        int r = s >> 3, c = (s & 7) ^ (r & 7);
        int ch = koff + c * 8;
        f16x8 u = *(const f16x8*)&ysrc[(size_t)(row0 + r) * 128 + ch];
        f16x8 sc8 = *(const f16x8*)&scf[ch];
        f16x8 sf8 = *(const f16x8*)&shf[ch];
        u = __builtin_elementwise_max(sc8 * u + sf8, zero);
        *(f16x8*)&As[s * 8] = u;
      }
    } else {
      const f16* Abase = (kc < 2) ? ysrc : xa;
      int koff = (kc & 1) * 64;
#pragma unroll
      for (int i = 0; i < 4; ++i) {
        int s = (w * 4 + i) * 64 + lane;
        int r = s >> 3, c = (s & 7) ^ (r & 7);
        GLD(Abase + (size_t)(row0 + r) * 128 + koff + c * 8, &As[(w * 4 + i) * 512]);
      }
    }
    // B fragments for this kc straight into registers (L2-hot; row = ni*16+l16)
    f16x8 bf[16];
#pragma unroll
    for (int ks = 0; ks < 2; ++ks)
#pragma unroll
      for (int ni = 0; ni < 8; ++ni)
        bf[ks * 8 + ni] = *(const f16x8*)&Wc[(size_t)(ni * 16 + l16) * 256 + kc * 64 + ks * 32 + quad * 8];
    __syncthreads();  // drains vmcnt (A GLD + B loads) + lgkmcnt (ds_write) + barrier
#pragma unroll
    for (int ks = 0; ks < 2; ++ks) {
      int cc = ks * 4 + quad;
      f16x8 af0, af1;
      {
        int rr = w * 16 + l16;
        af0 = *(const f16x8*)&As[(rr * 8 + (cc ^ (rr & 7))) * 8];
        int rr1 = 64 + rr;
        af1 = *(const f16x8*)&As[(rr1 * 8 + (cc ^ (rr1 & 7))) * 8];
      }
#pragma unroll
      for (int ni = 0; ni < 8; ++ni) {
        acc[0][ni] = __builtin_amdgcn_mfma_f32_16x16x32_f16(af0, bf[ks * 8 + ni], acc[0][ni], 0, 0, 0);
        acc[1][ni] = __builtin_amdgcn_mfma_f32_16x16x32_f16(af1, bf[ks * 8 + ni], acc[1][ni], 0, 0, 0);
      }
    }
    __syncthreads();  // all waves done reading As before next kc overwrites it
  }

  float b0c[8], b1c[8];
#pragma unroll
  for (int ni = 0; ni < 8; ++ni) {
    b0c[ni] = b0[ni * 16 + l16];
    b1c[ni] = b1[ni * 16 + l16];
  }
  float csum[8] = {}, csq[8] = {};
  // C/D layout: col = l16, row = quad*4 + reg (within each row-group)
#pragma unroll
  for (int rg = 0; rg < 2; ++rg) {
#pragma unroll
    for (int reg = 0; reg < 4; ++reg) {
      int v = row0 + rg * 64 + w * 16 + quad * 4 + reg;
      if (v < V_N) {
        float dv = dinv[v], gf = degf[v];
#pragma unroll
        for (int ni = 0; ni < 8; ++ni) {
          float tv = dv * (acc[rg][ni][reg] + b0c[ni] + gf * b1c[ni]);
          tbuf[(size_t)v * 128 + ni * 16 + l16] = (f16)tv;
          csum[ni] += tv;
          csq[ni] += tv * tv;
        }
      }
    }
  }
#pragma unroll
  for (int ni = 0; ni < 8; ++ni) {
    csum[ni] += __shfl_xor(csum[ni], 16);
    csum[ni] += __shfl_xor(csum[ni], 32);
    csq[ni] += __shfl_xor(csq[ni], 16);
    csq[ni] += __shfl_xor(csq[ni], 32);
  }
  if (quad == 0) {
#pragma unroll
    for (int ni = 0; ni < 8; ++ni) {
      atomicAdd(&sstat[ni * 16 + l16], csum[ni]);
      atomicAdd(&sstat[128 + ni * 16 + l16], csq[ni]);
    }
  }
  __syncthreads();
  atomicAdd(&statsN[(blockIdx.x & (NSH - 1)) * 256 + tid], sstat[tid]);  // 8-way sharded
}

// ----------------- final: out = relu(scale*t + shift + res), res from f16 y -----------------
__global__ __launch_bounds__(256) void k_final(const f16* __restrict__ t, const f16* __restrict__ yres,
                                               const float* __restrict__ gamma, const float* __restrict__ beta,
                                               const float* __restrict__ stats, float* __restrict__ out) {
  __shared__ float sred[256];
  __shared__ float scl[128], sfl[128];
  int tid = threadIdx.x;
  float a = 0.f;
#pragma unroll
  for (int h = 0; h < NSH; ++h) a += stats[h * 256 + tid];
  sred[tid] = a;
  __syncthreads();
  if (tid < 128) {
    float s = sred[tid], sq = sred[128 + tid];
    float mu = s * (1.0f / V_N);
    float var = sq * (1.0f / V_N) - mu * mu;
    float scv = gamma[tid] * rsqrtf(var + EPSV);
    scl[tid] = scv;
    sfl[tid] = beta[tid] - mu * scv;
  }
  __syncthreads();
  int q = blockIdx.x * 256 + tid;  // float4 index; 12500*256 == V_N*32 exactly
  int c4 = (q & 31) * 4;
  f16x4 tv = *(const f16x4*)&t[(size_t)q * 4];
  f16x4 rv = *(const f16x4*)&yres[(size_t)q * 4];
  float4 o;
  o.x = fmaxf(scl[c4 + 0] * (float)tv[0] + sfl[c4 + 0] + (float)rv[0], 0.f);
  o.y = fmaxf(scl[c4 + 1] * (float)tv[1] + sfl[c4 + 1] + (float)rv[1], 0.f);
  o.z = fmaxf(scl[c4 + 2] * (float)tv[2] + sfl[c4 + 2] + (float)rv[2], 0.f);
  o.w = fmaxf(scl[c4 + 3] * (float)tv[3] + sfl[c4 + 3] + (float)rv[3], 0.f);
  ((float4*)out)[q] = o;
}

extern "C" void kernel_launch(void* const* d_in, const int* in_sizes, int n_in,
                              void* d_out, int out_size, void* d_ws, size_t ws_size,
                              hipStream_t stream) {
  const float* features = (const float*)d_in[0];
  const int* edges = (const int*)d_in[1];
  const float* W0 = (const float*)d_in[2];
  const float* b0 = (const float*)d_in[3];
  const float* W1 = (const float*)d_in[4];
  const float* b1 = (const float*)d_in[5];
  const float* gamma = (const float*)d_in[6];
  const float* beta = (const float*)d_in[7];
  float* out = (float*)d_out;

  char* ws = (char*)d_ws;
  size_t off = 0;
  auto alloc = [&](size_t bytes) -> void* {
    void* p = ws + off;
    off = (off + bytes + 255) & ~(size_t)255;
    return p;
  };
  int* deg = (int*)alloc((size_t)V_N * 4);
  int* cursor = (int*)alloc((size_t)V_N * 4);
  int* csr_off = (int*)alloc((size_t)(V_N + 1) * 4);
  int* adj = (int*)alloc((size_t)2 * E_N * 4);
  int* adjell = (int*)alloc((size_t)V_N * 8 * 4);
  float* dinv = (float*)alloc((size_t)V_N * 4);
  float* degf = (float*)alloc((size_t)V_N * 4);
  int* csum = (int*)alloc(512 * 4);
  float* stats0 = (float*)alloc((size_t)NSH * 256 * 4);
  float* stats1 = (float*)alloc((size_t)NSH * 256 * 4);
  f16* y = (f16*)alloc((size_t)MPAD * 128 * 2);
  f16* xa = (f16*)alloc((size_t)MPAD * 128 * 2);
  f16* tbuf = (f16*)alloc((size_t)MPAD * 128 * 2);
  f16* Wcat = (f16*)alloc((size_t)3 * 128 * 256 * 2);

  // preamble: CSR + ELL8 + dinv/degf + weight prep + feature cast (5 dispatches)
  hipMemsetAsync(deg, 0, (size_t)V_N * 4, stream);
  k_countprep<<<2344 + 384 + 12500, 256, 0, stream>>>(edges, deg, W0, W1, Wcat, features, y);
  k_chunksum<<<NCHUNK, 256, 0, stream>>>(deg, csum);
  k_writeoff<<<NCHUNK, 256, 0, stream>>>(deg, csum, csr_off, dinv, degf, cursor);
  k_fill<<<(E_N + 255) / 256, 256, 0, stream>>>(edges, csr_off, cursor, adj, adjell);

  // layer 0: gather from y; gemm A y-half via GLD; stats -> stats0 (zeroed by gather<0>)
  k_gather<0><<<6250, 256, 0, stream>>>(tbuf, y, xa, deg, csr_off, adjell, adj,
                                        gamma, beta, stats0, stats0);
  k_gemm<0><<<NBLK_G, 256, 0, stream>>>(y, xa, Wcat, b0, b1, dinv, degf,
                                        gamma, beta, stats0, stats0, tbuf);
  // layer 1: BN(layer0) from stats0; stats -> stats1
  k_gather<1><<<6250, 256, 0, stream>>>(tbuf, y, xa, deg, csr_off, adjell, adj,
                                        gamma, beta, stats0, stats1);
  k_gemm<1><<<NBLK_G, 256, 0, stream>>>(tbuf, xa, Wcat + (size_t)1 * 128 * 256, b0 + D_N,
                                        b1 + D_N, dinv, degf, gamma, beta, stats0, stats1, tbuf);
  // layer 2: BN(layer1) from stats1; stats -> stats0
  k_gather<1><<<6250, 256, 0, stream>>>(tbuf, y, xa, deg, csr_off, adjell, adj,
                                        gamma + D_N, beta + D_N, stats1, stats0);
  k_gemm<1><<<NBLK_G, 256, 0, stream>>>(tbuf, xa, Wcat + (size_t)2 * 128 * 256, b0 + 2 * D_N,
                                        b1 + 2 * D_N, dinv, degf, gamma + D_N, beta + D_N,
                                        stats1, stats0, tbuf);
  // final: BN(layer2) from stats0 + residual (f16 y) + relu
  k_final<<<12500, 256, 0, stream>>>(tbuf, y, gamma + 2 * D_N, beta + 2 * D_N, stats0, out);
}

// Round 12
// 334.519 us; speedup vs baseline: 1.1649x; 1.1649x over previous
//
#include <hip/hip_runtime.h>
#include <math.h>
#include <stdint.h>

#define V_N 100000
#define E_N 300000
#define D_N 128
#define EPSV 1e-5f
#define NCHUNK 391   // ceil(V_N/256)
#define MPAD 100096  // 1564 * 64
#define NBLK_G 782   // MPAD/128 gemm blocks (128-row tiles)
#define NSH 8        // stats shards

typedef _Float16 f16;
typedef f16 f16x8 __attribute__((ext_vector_type(8)));
typedef f16 f16x4 __attribute__((ext_vector_type(4)));
typedef f16 f16x2 __attribute__((ext_vector_type(2)));
typedef float f32x4 __attribute__((ext_vector_type(4)));

// async global->LDS, 16B per lane; lds base must be wave-uniform
#define GLD(g, l) __builtin_amdgcn_global_load_lds( \
    (__attribute__((address_space(1))) void*)(g),   \
    (__attribute__((address_space(3))) void*)(l), 16, 0, 0)

// ----------------- merged: edge-degree count + weight prep + feature cast -----------------
// blocks [0,2344): count; [2344,2728): Wcat[l][n][k] half, k=[W0 row|W1 row]; rest: f16 cast.
__global__ __launch_bounds__(256) void k_countprep(const int* __restrict__ edges, int* __restrict__ deg,
                                                   const float* __restrict__ W0, const float* __restrict__ W1,
                                                   f16* __restrict__ Wc, const float* __restrict__ x,
                                                   f16* __restrict__ y) {
  int b = blockIdx.x;
  if (b < 2344) {
    int i = b * 256 + threadIdx.x;
    if (i < 2 * E_N) atomicAdd(&deg[edges[i]], 1);
  } else if (b < 2344 + 384) {  // 384*256 == 3*128*256 exactly
    int idx = (b - 2344) * 256 + threadIdx.x;
    int l = idx >> 15;
    int rem = idx & 32767;
    int n = rem >> 8, k = rem & 255;
    float v = (k < 128) ? W0[l * 16384 + n * 128 + k] : W1[l * 16384 + n * 128 + (k - 128)];
    Wc[idx] = (f16)v;
  } else {
    int q = (b - 2344 - 384) * 256 + threadIdx.x;  // 12500*256 == V_N*32 exactly
    float4 xv = ((const float4*)x)[q];
    f16x4 h;
    h[0] = (f16)xv.x; h[1] = (f16)xv.y; h[2] = (f16)xv.z; h[3] = (f16)xv.w;
    *(f16x4*)&y[(size_t)q * 4] = h;
  }
}

__global__ __launch_bounds__(256) void k_chunksum(const int* __restrict__ deg, int* __restrict__ csum) {
  __shared__ int red[256];
  int c = blockIdx.x, t = threadIdx.x;
  int i = c * 256 + t;
  red[t] = (i < V_N) ? deg[i] : 0;
  __syncthreads();
  for (int s = 128; s > 0; s >>= 1) {
    if (t < s) red[t] += red[t + s];
    __syncthreads();
  }
  if (t == 0) csum[c] = red[0];
}

// per-block redundant chunk-offset (sum csum[j<c], L2-hot) replaces the k_scanchunks
// dispatch; then intra-chunk scan. Also zeroes the fill cursor (deg stays = true degree).
__global__ __launch_bounds__(256) void k_writeoff(const int* __restrict__ deg, const int* __restrict__ csum,
                                                  int* __restrict__ csr_off, float* __restrict__ dinv,
                                                  float* __restrict__ degf, int* __restrict__ cursor) {
  __shared__ int sh[256];
  __shared__ int sbase;
  int c = blockIdx.x, t = threadIdx.x;
  // exclusive chunk offset: sum of csum[0..c-1]
  int x = (t < c) ? csum[t] : 0;
  if (256 + t < c) x += csum[256 + t];  // c <= 390 < 512
  sh[t] = x;
  __syncthreads();
  for (int s = 128; s > 0; s >>= 1) {
    if (t < s) sh[t] += sh[t + s];
    __syncthreads();
  }
  if (t == 0) sbase = sh[0];
  __syncthreads();
  int base = sbase;
  __syncthreads();  // done reading sh[0]; safe to reuse sh
  int i = c * 256 + t;
  int v = (i < V_N) ? deg[i] : 0;
  sh[t] = v;
  __syncthreads();
  for (int s = 1; s < 256; s <<= 1) {
    int xx = (t >= s) ? sh[t - s] : 0;
    __syncthreads();
    sh[t] += xx;
    __syncthreads();
  }
  int excl = sh[t] - v;
  if (i <= V_N) csr_off[i] = base + excl;
  if (i < V_N) {
    dinv[i] = 1.0f / (1.0f + (float)v);
    degf[i] = (float)v;
    cursor[i] = 0;
  }
}

// fills CSR adj AND the ELL8 fast-path array (first 8 neighbors at adjell[v*8+j]).
// Slots j >= deg stay uninitialized (workspace garbage) -> consumer clamps before use.
__global__ __launch_bounds__(256) void k_fill(const int* __restrict__ edges, const int* __restrict__ csr_off,
                                              int* __restrict__ cursor, int* __restrict__ adj,
                                              int* __restrict__ adjell) {
  int e = blockIdx.x * blockDim.x + threadIdx.x;
  if (e >= E_N) return;
  int s = edges[2 * e], d = edges[2 * e + 1];
  int p = atomicAdd(&cursor[s], 1);
  adj[csr_off[s] + p] = d;
  if (p < 8) adjell[s * 8 + p] = d;
  int q = atomicAdd(&cursor[d], 1);
  adj[csr_off[d] + q] = s;
  if (q < 8) adjell[d * 8 + q] = s;
}

// ----------------- gather: quad-per-vertex, dwordx4 row loads, packed-f16 math ----------
// Wave = 4 quads; quad q owns one vertex, lane l16 owns one 16B channel chunk (8 halves).
// MODE 0: neighbors from y (raw). MODE 1: neighbors from tin with relu(scale*t+shift),
//   scale/shift recomputed per block from statsP (8 shards from the previous gemm).
// f16 accumulation throughout. __launch_bounds__(256,8) pins <=64 VGPR -> 32 waves/CU.
// Blocks 0..7 zero statsN. Grid: 6250 x 4 waves x 4 quads = 100000.
template <int MODE>
__global__ __launch_bounds__(256, 8) void k_gather(const f16* __restrict__ tin, const f16* __restrict__ y,
                                                   f16* __restrict__ xa, const int* __restrict__ deg,
                                                   const int* __restrict__ csr_off,
                                                   const int* __restrict__ adjell, const int* __restrict__ adj,
                                                   const float* __restrict__ gamma, const float* __restrict__ beta,
                                                   const float* __restrict__ statsP, float* __restrict__ statsN) {
  __shared__ float sred[256];
  __shared__ float scl[128], sfl[128];
  int tid = threadIdx.x;
  if (blockIdx.x < NSH) statsN[blockIdx.x * 256 + tid] = 0.f;
  int w = tid >> 6, lane = tid & 63;
  int q = lane >> 4, l16 = lane & 15;
  int v = (blockIdx.x * 4 + w) * 4 + q;  // this lane's vertex (exactly covers [0, V_N))
  int co = l16 * 8;                      // channel base, 8 halves = 16B
  const f16* base = MODE ? tin : y;
  int dg = deg[v];
  int s0 = csr_off[v];
  int4 ia = *(const int4*)&adjell[v * 8];
  int4 ib = *(const int4*)&adjell[v * 8 + 4];
  f16x8 scv = {}, sfv = {};
  if (MODE) {
    // per-block redundant BN finalize (identical f32 math in every block)
    float a = 0.f;
#pragma unroll
    for (int h = 0; h < NSH; ++h) a += statsP[h * 256 + tid];
    sred[tid] = a;
    __syncthreads();
    if (tid < 128) {
      float s = sred[tid], sq = sred[128 + tid];
      float mu = s * (1.0f / V_N);
      float var = sq * (1.0f / V_N) - mu * mu;
      float scvf = gamma[tid] * rsqrtf(var + EPSV);
      scl[tid] = scvf;
      sfl[tid] = beta[tid] - mu * scvf;
    }
    __syncthreads();
#pragma unroll
    for (int k = 0; k < 8; ++k) {
      scv[k] = (f16)scl[co + k];
      sfv[k] = (f16)sfl[co + k];
    }
  }
  int idx[8] = {ia.x, ia.y, ia.z, ia.w, ib.x, ib.y, ib.z, ib.w};
#pragma unroll
  for (int j = 0; j < 8; ++j) idx[j] = ((unsigned)idx[j] < (unsigned)V_N) ? idx[j] : 0;
  f16x8 h[8];
#pragma unroll
  for (int j = 0; j < 8; ++j) h[j] = *(const f16x8*)&base[(size_t)idx[j] * 128 + co];
  f16x8 zero = {};
#pragma unroll
  for (int j = 0; j < 8; ++j) {
    f16x8 u = h[j];
    if (MODE) u = __builtin_elementwise_max(scv * u + sfv, zero);
    h[j] = (j < dg) ? u : zero;
  }
  f16x8 t01 = h[0] + h[1], t23 = h[2] + h[3], t45 = h[4] + h[5], t67 = h[6] + h[7];
  f16x8 accv = (t01 + t23) + (t45 + t67);
  // tail for deg > 8 (divergent at quad granularity; P ~ 11% of vertices)
  for (int p = 8; p < dg; p += 8) {
    int id2[8];
#pragma unroll
    for (int j = 0; j < 8; ++j) {
      int pp = p + j;
      id2[j] = adj[s0 + (pp < dg ? pp : dg - 1)];
    }
    f16x8 g[8];
#pragma unroll
    for (int j = 0; j < 8; ++j) g[j] = *(const f16x8*)&base[(size_t)id2[j] * 128 + co];
#pragma unroll
    for (int j = 0; j < 8; ++j) {
      f16x8 u = g[j];
      if (MODE) u = __builtin_elementwise_max(scv * u + sfv, zero);
      g[j] = (p + j < dg) ? u : zero;
    }
    accv = accv + (((g[0] + g[1]) + (g[2] + g[3])) + ((g[4] + g[5]) + (g[6] + g[7])));
  }
  *(f16x8*)&xa[(size_t)v * 128 + co] = accv;
}

// ----------------- fused GEMM: t = dinv * ([act|xa] @ Wcat^T + b0 + deg*b1); + BN stats ---
// 128 rows x 128 cols per block (782 blocks), K=256 in 4 chunks of 64 halves.
// Wave w owns rows {rg*64 + w*16 + l16 : rg=0,1}; B fragments shared across both row-groups.
// MODE 0: A y-half = ysrc (raw f16) via global_load_lds.
// MODE 1: A y-half reg-staged from ysrc(=t, in-place safe) with relu(scale*t+shift);
//   scale/shift recomputed per block from statsP (previous layer's stats, prev kernel).
// Stats for THIS layer go to statsN (8-way sharded, zeroed by the preceding gather).
template <int MODE>
__global__ __launch_bounds__(256) void k_gemm(const f16* ysrc, const f16* __restrict__ xa,
                                              const f16* __restrict__ Wc,
                                              const float* __restrict__ b0, const float* __restrict__ b1,
                                              const float* __restrict__ dinv, const float* __restrict__ degf,
                                              const float* __restrict__ gammaP, const float* __restrict__ betaP,
                                              const float* __restrict__ statsP, float* __restrict__ statsN,
                                              f16* tbuf) {
  __shared__ __align__(16) f16 As[128 * 64];   // 1024 x 16B chunks, chunk (r,c) at slot r*8 + (c^(r&7))
  __shared__ __align__(16) f16 Bs[128 * 64];   // 1024 x 16B chunks
  __shared__ float sstat[256];
  __shared__ __align__(16) f16 scf[128], shf[128];
  int tid = threadIdx.x;
  int w = tid >> 6, lane = tid & 63;
  int quad = lane >> 4, l16 = lane & 15;
  int row0 = blockIdx.x * 128;
  f32x4 acc[2][8] = {};
  if (MODE) {
    // per-block redundant BN finalize of the PREVIOUS layer (uses sstat as scratch)
    float a = 0.f;
#pragma unroll
    for (int h = 0; h < NSH; ++h) a += statsP[h * 256 + tid];
    sstat[tid] = a;
    __syncthreads();
    if (tid < 128) {
      float s = sstat[tid], sq = sstat[128 + tid];
      float mu = s * (1.0f / V_N);
      float var = sq * (1.0f / V_N) - mu * mu;
      float scv = gammaP[tid] * rsqrtf(var + EPSV);
      scf[tid] = (f16)scv;
      shf[tid] = (f16)(betaP[tid] - mu * scv);
    }
    __syncthreads();
  }
  sstat[tid] = 0.f;  // visible before epilogue use via the kc-loop barriers

  for (int kc = 0; kc < 4; ++kc) {
    if (MODE && kc < 2) {
      // reg-stage A from t with on-the-fly BN+relu (identical f16 math to gather's path)
      int koff = kc * 64;
      f16x8 zero = {};
#pragma unroll
      for (int i = 0; i < 4; ++i) {
        int s = (w * 4 + i) * 64 + lane;
        int r = s >> 3, c = (s & 7) ^ (r & 7);
        int ch = koff + c * 8;
        f16x8 u = *(const f16x8*)&ysrc[(size_t)(row0 + r) * 128 + ch];
        f16x8 sc8 = *(const f16x8*)&scf[ch];
        f16x8 sf8 = *(const f16x8*)&shf[ch];
        u = __builtin_elementwise_max(sc8 * u + sf8, zero);
        *(f16x8*)&As[s * 8] = u;
      }
    } else {
      const f16* Abase = (kc < 2) ? ysrc : xa;
      int koff = (kc & 1) * 64;
#pragma unroll
      for (int i = 0; i < 4; ++i) {
        int s = (w * 4 + i) * 64 + lane;
        int r = s >> 3, c = (s & 7) ^ (r & 7);
        GLD(Abase + (size_t)(row0 + r) * 128 + koff + c * 8, &As[(w * 4 + i) * 512]);
      }
    }
    // stage B: 1024 chunks, 4 per wave
#pragma unroll
    for (int i = 0; i < 4; ++i) {
      int s = (w * 4 + i) * 64 + lane;
      int r = s >> 3, c = (s & 7) ^ (r & 7);
      GLD(Wc + (size_t)r * 256 + kc * 64 + c * 8, &Bs[(w * 4 + i) * 512]);
    }
    __syncthreads();  // drains vmcnt (GLD) + lgkmcnt (ds_write) + barrier
#pragma unroll
    for (int ks = 0; ks < 2; ++ks) {
      int cc = ks * 4 + quad;
      f16x8 af0, af1;
      {
        int rr = w * 16 + l16;
        af0 = *(const f16x8*)&As[(rr * 8 + (cc ^ (rr & 7))) * 8];
        int rr1 = 64 + rr;
        af1 = *(const f16x8*)&As[(rr1 * 8 + (cc ^ (rr1 & 7))) * 8];
      }
#pragma unroll
      for (int ni = 0; ni < 8; ++ni) {
        int rb = ni * 16 + l16;
        f16x8 bf = *(const f16x8*)&Bs[(rb * 8 + (cc ^ (rb & 7))) * 8];
        acc[0][ni] = __builtin_amdgcn_mfma_f32_16x16x32_f16(af0, bf, acc[0][ni], 0, 0, 0);
        acc[1][ni] = __builtin_amdgcn_mfma_f32_16x16x32_f16(af1, bf, acc[1][ni], 0, 0, 0);
      }
    }
    __syncthreads();
  }

  float b0c[8], b1c[8];
#pragma unroll
  for (int ni = 0; ni < 8; ++ni) {
    b0c[ni] = b0[ni * 16 + l16];
    b1c[ni] = b1[ni * 16 + l16];
  }
  float csum[8] = {}, csq[8] = {};
  // C/D layout: col = l16, row = quad*4 + reg (within each row-group)
#pragma unroll
  for (int rg = 0; rg < 2; ++rg) {
#pragma unroll
    for (int reg = 0; reg < 4; ++reg) {
      int v = row0 + rg * 64 + w * 16 + quad * 4 + reg;
      if (v < V_N) {
        float dv = dinv[v], gf = degf[v];
#pragma unroll
        for (int ni = 0; ni < 8; ++ni) {
          float tv = dv * (acc[rg][ni][reg] + b0c[ni] + gf * b1c[ni]);
          tbuf[(size_t)v * 128 + ni * 16 + l16] = (f16)tv;
          csum[ni] += tv;
          csq[ni] += tv * tv;
        }
      }
    }
  }
#pragma unroll
  for (int ni = 0; ni < 8; ++ni) {
    csum[ni] += __shfl_xor(csum[ni], 16);
    csum[ni] += __shfl_xor(csum[ni], 32);
    csq[ni] += __shfl_xor(csq[ni], 16);
    csq[ni] += __shfl_xor(csq[ni], 32);
  }
  if (quad == 0) {
#pragma unroll
    for (int ni = 0; ni < 8; ++ni) {
      atomicAdd(&sstat[ni * 16 + l16], csum[ni]);
      atomicAdd(&sstat[128 + ni * 16 + l16], csq[ni]);
    }
  }
  __syncthreads();
  atomicAdd(&statsN[(blockIdx.x & (NSH - 1)) * 256 + tid], sstat[tid]);  // 8-way sharded
}

// ----------------- final: out = relu(scale*t + shift + res), res from f16 y -----------------
__global__ __launch_bounds__(256) void k_final(const f16* __restrict__ t, const f16* __restrict__ yres,
                                               const float* __restrict__ gamma, const float* __restrict__ beta,
                                               const float* __restrict__ stats, float* __restrict__ out) {
  __shared__ float sred[256];
  __shared__ float scl[128], sfl[128];
  int tid = threadIdx.x;
  float a = 0.f;
#pragma unroll
  for (int h = 0; h < NSH; ++h) a += stats[h * 256 + tid];
  sred[tid] = a;
  __syncthreads();
  if (tid < 128) {
    float s = sred[tid], sq = sred[128 + tid];
    float mu = s * (1.0f / V_N);
    float var = sq * (1.0f / V_N) - mu * mu;
    float scv = gamma[tid] * rsqrtf(var + EPSV);
    scl[tid] = scv;
    sfl[tid] = beta[tid] - mu * scv;
  }
  __syncthreads();
  int q = blockIdx.x * 256 + tid;  // float4 index; 12500*256 == V_N*32 exactly
  int c4 = (q & 31) * 4;
  f16x4 tv = *(const f16x4*)&t[(size_t)q * 4];
  f16x4 rv = *(const f16x4*)&yres[(size_t)q * 4];
  float4 o;
  o.x = fmaxf(scl[c4 + 0] * (float)tv[0] + sfl[c4 + 0] + (float)rv[0], 0.f);
  o.y = fmaxf(scl[c4 + 1] * (float)tv[1] + sfl[c4 + 1] + (float)rv[1], 0.f);
  o.z = fmaxf(scl[c4 + 2] * (float)tv[2] + sfl[c4 + 2] + (float)rv[2], 0.f);
  o.w = fmaxf(scl[c4 + 3] * (float)tv[3] + sfl[c4 + 3] + (float)rv[3], 0.f);
  ((float4*)out)[q] = o;
}

extern "C" void kernel_launch(void* const* d_in, const int* in_sizes, int n_in,
                              void* d_out, int out_size, void* d_ws, size_t ws_size,
                              hipStream_t stream) {
  const float* features = (const float*)d_in[0];
  const int* edges = (const int*)d_in[1];
  const float* W0 = (const float*)d_in[2];
  const float* b0 = (const float*)d_in[3];
  const float* W1 = (const float*)d_in[4];
  const float* b1 = (const float*)d_in[5];
  const float* gamma = (const float*)d_in[6];
  const float* beta = (const float*)d_in[7];
  float* out = (float*)d_out;

  char* ws = (char*)d_ws;
  size_t off = 0;
  auto alloc = [&](size_t bytes) -> void* {
    void* p = ws + off;
    off = (off + bytes + 255) & ~(size_t)255;
    return p;
  };
  int* deg = (int*)alloc((size_t)V_N * 4);
  int* cursor = (int*)alloc((size_t)V_N * 4);
  int* csr_off = (int*)alloc((size_t)(V_N + 1) * 4);
  int* adj = (int*)alloc((size_t)2 * E_N * 4);
  int* adjell = (int*)alloc((size_t)V_N * 8 * 4);
  float* dinv = (float*)alloc((size_t)V_N * 4);
  float* degf = (float*)alloc((size_t)V_N * 4);
  int* csum = (int*)alloc(512 * 4);
  float* stats0 = (float*)alloc((size_t)NSH * 256 * 4);
  float* stats1 = (float*)alloc((size_t)NSH * 256 * 4);
  f16* y = (f16*)alloc((size_t)MPAD * 128 * 2);
  f16* xa = (f16*)alloc((size_t)MPAD * 128 * 2);
  f16* tbuf = (f16*)alloc((size_t)MPAD * 128 * 2);
  f16* Wcat = (f16*)alloc((size_t)3 * 128 * 256 * 2);

  // preamble: CSR + ELL8 + dinv/degf + weight prep + feature cast (5 dispatches)
  hipMemsetAsync(deg, 0, (size_t)V_N * 4, stream);
  k_countprep<<<2344 + 384 + 12500, 256, 0, stream>>>(edges, deg, W0, W1, Wcat, features, y);
  k_chunksum<<<NCHUNK, 256, 0, stream>>>(deg, csum);
  k_writeoff<<<NCHUNK, 256, 0, stream>>>(deg, csum, csr_off, dinv, degf, cursor);
  k_fill<<<(E_N + 255) / 256, 256, 0, stream>>>(edges, csr_off, cursor, adj, adjell);

  // layer 0: gather from y; gemm A y-half via GLD; stats -> stats0 (zeroed by gather<0>)
  k_gather<0><<<6250, 256, 0, stream>>>(tbuf, y, xa, deg, csr_off, adjell, adj,
                                        gamma, beta, stats0, stats0);
  k_gemm<0><<<NBLK_G, 256, 0, stream>>>(y, xa, Wcat, b0, b1, dinv, degf,
                                        gamma, beta, stats0, stats0, tbuf);
  // layer 1: BN(layer0) from stats0; stats -> stats1
  k_gather<1><<<6250, 256, 0, stream>>>(tbuf, y, xa, deg, csr_off, adjell, adj,
                                        gamma, beta, stats0, stats1);
  k_gemm<1><<<NBLK_G, 256, 0, stream>>>(tbuf, xa, Wcat + (size_t)1 * 128 * 256, b0 + D_N,
                                        b1 + D_N, dinv, degf, gamma, beta, stats0, stats1, tbuf);
  // layer 2: BN(layer1) from stats1; stats -> stats0
  k_gather<1><<<6250, 256, 0, stream>>>(tbuf, y, xa, deg, csr_off, adjell, adj,
                                        gamma + D_N, beta + D_N, stats1, stats0);
  k_gemm<1><<<NBLK_G, 256, 0, stream>>>(tbuf, xa, Wcat + (size_t)2 * 128 * 256, b0 + 2 * D_N,
                                        b1 + 2 * D_N, dinv, degf, gamma + D_N, beta + D_N,
                                        stats1, stats0, tbuf);
  // final: BN(layer2) from stats0 + residual (f16 y) + relu
  k_final<<<12500, 256, 0, stream>>>(tbuf, y, gamma + 2 * D_N, beta + 2 * D_N, stats0, out);
}